// Round 8
// baseline (258.319 us; speedup 1.0000x reference)
//
#include <hip/hip_runtime.h>
#include <stdint.h>

#define THREADS 256
#define EPB     65536            // elements per block for streaming kernels
#define NBINS   4096             // 12-bit coarse histogram
#define ITERS   (EPB / 4 / THREADS)
#define CNT_STRIDE 16            // candCnt padded: one 64B cacheline per row
#define LDSCAP  8192             // per-block LDS candidate buffer (32 KB)
#define K4T     1024             // k4 block size (16 waves)
#define SAMPLE_STRIDE 64         // float4 stride for sampling (1/64 of data)
#define SMARGIN 600              // sample-rank margin (~6.6 sigma)

typedef float vfloat4 __attribute__((ext_vector_type(4)));  // native vec for NT store

// Order-preserving float -> uint transform (uint compare == float compare)
__device__ __forceinline__ uint32_t f2u(float f) {
    uint32_t b = __float_as_uint(f);
    return (b & 0x80000000u) ? ~b : (b | 0x80000000u);
}
__device__ __forceinline__ float u2f(uint32_t u) {
    uint32_t b = (u & 0x80000000u) ? (u & 0x7FFFFFFFu) : ~u;
    return __uint_as_float(b);
}

// Block-wide double sum; valid on thread 0. Any blockDim multiple of 64.
// NOTE: caller must __syncthreads() between consecutive calls (shared wsum reuse).
__device__ __forceinline__ double blockReduceSum(double v) {
    for (int off = 32; off > 0; off >>= 1) v += __shfl_down(v, off, 64);
    __shared__ double wsum[16];
    int lane = threadIdx.x & 63, wid = threadIdx.x >> 6;
    if (lane == 0) wsum[wid] = v;
    __syncthreads();
    double r = 0.0;
    if (threadIdx.x == 0) {
        int nw = (int)(blockDim.x >> 6);
        for (int i = 0; i < nw; ++i) r += wsum[i];
    }
    return r;
}

// K0: zero the accumulator region of the workspace
__global__ void __launch_bounds__(THREADS) k0_zero(uint4* __restrict__ p, int n16) {
    int idx = blockIdx.x * THREADS + threadIdx.x;
    int stride = gridDim.x * THREADS;
    uint4 z = {0u, 0u, 0u, 0u};
    for (int i = idx; i < n16; i += stride) p[i] = z;
}

// KS: sampled (1/64) per-row coarse histogram -> window [lo,hi] of coarse bins
//     guaranteed (w.h.p.; verified exactly in k2) to contain a*.
__global__ void __launch_bounds__(THREADS) kS_window(
    const float* __restrict__ x, const float* __restrict__ probs,
    uint32_t* __restrict__ winLo, uint32_t* __restrict__ winHi, int n) {
    int row = blockIdx.x;
    __shared__ uint32_t hist[NBINS];
    __shared__ uint32_t part[THREADS];
    for (int i = threadIdx.x; i < NBINS; i += THREADS) hist[i] = 0;
    __syncthreads();
    const float4* p = (const float4*)(x + (size_t)row * n);
    int nf4 = n / 4;
    int ns4 = nf4 / SAMPLE_STRIDE;                 // sampled float4 per row
    for (int i = threadIdx.x; i < ns4; i += THREADS) {
        float4 v = p[(size_t)i * SAMPLE_STRIDE];
        atomicAdd(&hist[f2u(v.x) >> 20], 1u);
        atomicAdd(&hist[f2u(v.y) >> 20], 1u);
        atomicAdd(&hist[f2u(v.z) >> 20], 1u);
        atomicAdd(&hist[f2u(v.w) >> 20], 1u);
    }
    __syncthreads();
    uint32_t sLoc = 0;
    for (int j = 0; j < NBINS / THREADS; ++j) sLoc += hist[threadIdx.x * (NBINS / THREADS) + j];
    part[threadIdx.x] = sLoc;
    __syncthreads();
    if (threadIdx.x == 0) {
        long long nS = (long long)ns4 * 4;
        float pr = probs[row];
        float t = ceilf((float)n * pr);
        long long idx = (long long)t - 1; if (idx < 0) idx = 0;
        unsigned long long k = (unsigned long long)idx + 1;    // 1-indexed true rank
        long long rS = (long long)((k * (unsigned long long)nS) / (unsigned long long)n);
        long long loT = rS - SMARGIN;
        long long hiT = rS + SMARGIN;
        int lo, hi;
        if (loT <= 0) lo = 0;
        else {
            uint32_t T = (uint32_t)loT, cum = 0; int ch = 0;
            for (; ch < THREADS - 1; ++ch) { if (cum + part[ch] >= T) break; cum += part[ch]; }
            int b = ch * (NBINS / THREADS);
            for (;; ++b) { uint32_t cb = hist[b]; if (cum + cb >= T || b == NBINS - 1) break; cum += cb; }
            lo = b;
        }
        if (hiT >= nS) hi = NBINS - 1;
        else {
            uint32_t T = (uint32_t)hiT, cum = 0; int ch = 0;
            for (; ch < THREADS - 1; ++ch) { if (cum + part[ch] >= T) break; cum += part[ch]; }
            int b = ch * (NBINS / THREADS);
            for (;; ++b) { uint32_t cb = hist[b]; if (cum + cb >= T || b == NBINS - 1) break; cum += cb; }
            hi = b;
        }
        if (hi < lo) hi = lo;
        winLo[row] = (uint32_t)lo;
        winHi[row] = (uint32_t)hi;
    }
}

// K13: ONE full pass over x: exact coarse hist + rowSum + sumGt(bins>hi) +
//      candidate compaction for coarse bins in [lo,hi] (LDS-staged).
__global__ void __launch_bounds__(THREADS) k13_main(
    const float* __restrict__ x, const uint32_t* __restrict__ winLo,
    const uint32_t* __restrict__ winHi, uint32_t* __restrict__ ghist,
    double* __restrict__ rowSum, double* __restrict__ rowSumGtWin,
    uint32_t* __restrict__ cand, uint32_t* __restrict__ candCount,
    int blocksPerRow, int cap, int n) {
    __shared__ uint32_t hist[NBINS];
    __shared__ uint32_t lbuf[LDSCAP];
    __shared__ uint32_t lcnt, gbase;
    for (int i = threadIdx.x; i < NBINS; i += THREADS) hist[i] = 0;
    if (threadIdx.x == 0) lcnt = 0;
    __syncthreads();

    int row   = blockIdx.x / blocksPerRow;
    int chunk = blockIdx.x % blocksPerRow;
    uint32_t lo = winLo[row], hi = winHi[row];
    uint32_t* cl = cand + (size_t)row * cap;
    uint32_t* cc = candCount + (size_t)row * CNT_STRIDE;
    const float4* p = (const float4*)(x + (size_t)row * n + (size_t)chunk * EPB);

    double s = 0.0, sGt = 0.0;
    #pragma unroll 4
    for (int it = 0; it < ITERS; ++it) {
        float4 v = p[it * THREADS + threadIdx.x];
        float vals[4] = {v.x, v.y, v.z, v.w};
        #pragma unroll
        for (int j = 0; j < 4; ++j) {
            uint32_t u = f2u(vals[j]);
            uint32_t b = u >> 20;
            atomicAdd(&hist[b], 1u);
            s += (double)vals[j];
            if (b > hi) sGt += (double)vals[j];
            else if (b >= lo) {
                uint32_t pos = atomicAdd(&lcnt, 1u);
                if (pos < LDSCAP) lbuf[pos] = u;
                else { uint32_t g = atomicAdd(cc, 1u); if ((int)g < cap) cl[g] = u; }
            }
        }
    }
    __syncthreads();
    uint32_t* gh = ghist + (size_t)row * NBINS;
    for (int i = threadIdx.x; i < NBINS; i += THREADS) {
        uint32_t hv = hist[i];
        if (hv) atomicAdd(&gh[i], hv);
    }
    uint32_t cnt = (lcnt < LDSCAP) ? lcnt : LDSCAP;
    if (threadIdx.x == 0) gbase = atomicAdd(cc, cnt);
    __syncthreads();
    uint32_t base = gbase;
    for (uint32_t i = threadIdx.x; i < cnt; i += THREADS) {
        uint32_t g = base + i;
        if ((int)g < cap) cl[g] = lbuf[i];
    }
    double bs = blockReduceSum(s);
    if (threadIdx.x == 0) atomicAdd(&rowSum[row], bs);
    __syncthreads();                                  // wsum reuse hazard
    double bg = blockReduceSum(sGt);
    if (threadIdx.x == 0) atomicAdd(&rowSumGtWin[row], bg);
}

// K2: exact scan -> a*, rank-within-a*; verify window & candidate capacity
__global__ void __launch_bounds__(THREADS) k2_select(
    const uint32_t* __restrict__ ghist, const float* __restrict__ probs,
    uint32_t* __restrict__ aStar, uint32_t* __restrict__ rankW,
    uint32_t* __restrict__ candCnt, const uint32_t* __restrict__ winLo,
    const uint32_t* __restrict__ winHi, uint32_t* __restrict__ flagOk,
    int cap, int n) {
    int row = blockIdx.x;
    const uint32_t* h = ghist + (size_t)row * NBINS;
    __shared__ uint32_t part[THREADS];
    uint32_t s = 0;
    #pragma unroll
    for (int i = 0; i < NBINS / THREADS; ++i) s += h[threadIdx.x * (NBINS / THREADS) + i];
    part[threadIdx.x] = s;
    __syncthreads();
    if (threadIdx.x == 0) {
        float p = probs[row];
        float t = ceilf((float)n * p);
        long long idx = (long long)t - 1;
        if (idx < 0) idx = 0;
        uint32_t k = (uint32_t)idx + 1;
        uint32_t cum = 0;
        int chunk = 0;
        for (; chunk < THREADS - 1; ++chunk) {
            if (cum + part[chunk] >= k) break;
            cum += part[chunk];
        }
        int bin = chunk * (NBINS / THREADS);
        for (;; ++bin) {
            uint32_t c = h[bin];
            if (cum + c >= k || bin == NBINS - 1) break;
            cum += c;
        }
        aStar[row] = (uint32_t)bin;
        rankW[row] = k - cum;
        uint32_t ccv = candCnt[(size_t)row * CNT_STRIDE];
        int ok = (bin >= (int)winLo[row] && bin <= (int)winHi[row] &&
                  ccv <= (uint32_t)cap) ? 1 : 0;
        flagOk[row] = (uint32_t)ok;
        if (!ok) candCnt[(size_t)row * CNT_STRIDE] = 0;   // fallback refills
    }
}

// K3FB: classic candidate pass — runs only if the window missed (early exit).
__global__ void __launch_bounds__(THREADS) k3_fallback(
    const float* __restrict__ x, const uint32_t* __restrict__ aStar,
    const uint32_t* __restrict__ flagOk,
    uint32_t* __restrict__ cand, uint32_t* __restrict__ candCount,
    double* __restrict__ rowSumGtFB, int blocksPerRow, int cap, int n) {
    int row   = blockIdx.x / blocksPerRow;
    if (flagOk[row]) return;
    __shared__ uint32_t lbuf[LDSCAP];
    __shared__ uint32_t lcnt, gbase;
    if (threadIdx.x == 0) lcnt = 0;
    __syncthreads();
    int chunk = blockIdx.x % blocksPerRow;
    uint32_t a = aStar[row];
    uint32_t* cl = cand + (size_t)row * cap;
    uint32_t* cc = candCount + (size_t)row * CNT_STRIDE;
    const float4* p = (const float4*)(x + (size_t)row * n + (size_t)chunk * EPB);

    double sg = 0.0;
    #pragma unroll 4
    for (int it = 0; it < ITERS; ++it) {
        float4 v = p[it * THREADS + threadIdx.x];
        float vals[4] = {v.x, v.y, v.z, v.w};
        #pragma unroll
        for (int j = 0; j < 4; ++j) {
            uint32_t u = f2u(vals[j]);
            uint32_t b = u >> 20;
            if (b > a) sg += (double)vals[j];
            else if (b == a) {
                uint32_t pos = atomicAdd(&lcnt, 1u);
                if (pos < LDSCAP) lbuf[pos] = u;
                else { uint32_t g = atomicAdd(cc, 1u); if ((int)g < cap) cl[g] = u; }
            }
        }
    }
    __syncthreads();
    uint32_t cnt = (lcnt < LDSCAP) ? lcnt : LDSCAP;
    if (threadIdx.x == 0) gbase = atomicAdd(cc, cnt);
    __syncthreads();
    uint32_t base = gbase;
    for (uint32_t i = threadIdx.x; i < cnt; i += THREADS) {
        uint32_t g = base + i;
        if ((int)g < cap) cl[g] = lbuf[i];
    }
    double bs = blockReduceSum(sg);
    if (threadIdx.x == 0) atomicAdd(&rowSumGtFB[row], bs);
}

// K4: two-pass select over (possibly multi-bin-window) candidates.
//  Pass A: among coarse==a*: hist+sum on bits[19:8] -> b1; candidates with
//          coarse>a* accumulate into sMid. Pass B: low byte -> b2.
//  prefix|b1|b2 fixes all 32 bits; b2-slot elements equal the threshold.
__global__ void __launch_bounds__(K4T) k4_final(
    const uint32_t* __restrict__ cand, const uint32_t* __restrict__ candCount,
    const uint32_t* __restrict__ aStar, const uint32_t* __restrict__ rankW,
    const double* __restrict__ rowSum, const double* __restrict__ rowSumGtWin,
    const double* __restrict__ rowSumGtFB, const uint32_t* __restrict__ flagOk,
    float* __restrict__ scaleArr, float* __restrict__ thrArr, int cap) {
    int row = blockIdx.x, tid = threadIdx.x;
    uint32_t c = candCount[(size_t)row * CNT_STRIDE];
    if (c > (uint32_t)cap) c = (uint32_t)cap;
    const uint32_t* cl = cand + (size_t)row * cap;
    uint32_t a = aStar[row];

    __shared__ uint32_t hcnt[4096];
    __shared__ double   hsum[4096];
    __shared__ uint32_t part1[K4T];
    __shared__ uint32_t part2[64];
    __shared__ uint32_t cnt256[256];
    __shared__ double   sum256[256];
    __shared__ uint32_t sh_b1, sh_r2, sh_b2;

    for (int i = tid; i < 4096; i += K4T) { hcnt[i] = 0; hsum[i] = 0.0; }
    for (int i = tid; i < 256;  i += K4T) { cnt256[i] = 0; sum256[i] = 0.0; }
    __syncthreads();

    // Pass A
    double sMid = 0.0;
    for (uint32_t i = tid; i < c; i += K4T) {
        uint32_t u = cl[i];
        uint32_t cb = u >> 20;
        if (cb == a) {
            uint32_t b = (u >> 8) & 0xFFFu;
            atomicAdd(&hcnt[b], 1u);
            atomicAdd(&hsum[b], (double)u2f(u));
        } else if (cb > a) {
            sMid += (double)u2f(u);
        }
    }
    __syncthreads();

    uint32_t p1 = hcnt[tid*4] + hcnt[tid*4+1] + hcnt[tid*4+2] + hcnt[tid*4+3];
    part1[tid] = p1;
    __syncthreads();
    if (tid < 64) {
        uint32_t s2 = 0;
        for (int j = 0; j < 16; ++j) s2 += part1[tid*16 + j];
        part2[tid] = s2;
    }
    __syncthreads();
    if (tid == 0) {
        uint32_t r = rankW[row], cum = 0;
        int j = 0;
        for (; j < 63; ++j) { if (cum + part2[j] >= r) break; cum += part2[j]; }
        int t = j * 16;
        for (; t < j*16 + 15; ++t) { if (cum + part1[t] >= r) break; cum += part1[t]; }
        int b = t * 4;
        for (; b < t*4 + 3; ++b) { if (cum + hcnt[b] >= r) break; cum += hcnt[b]; }
        sh_b1 = (uint32_t)b;
        sh_r2 = r - cum;
    }
    __syncthreads();
    uint32_t b1 = sh_b1;

    double g = 0.0;
    for (int i = tid; i < 4096; i += K4T) if (i > (int)b1) g += hsum[i];

    // Pass B
    for (uint32_t i = tid; i < c; i += K4T) {
        uint32_t u = cl[i];
        if ((u >> 20) == a && ((u >> 8) & 0xFFFu) == b1) {
            atomicAdd(&cnt256[u & 0xFFu], 1u);
            atomicAdd(&sum256[u & 0xFFu], (double)u2f(u));
        }
    }
    __syncthreads();
    if (tid == 0) {
        uint32_t r2 = sh_r2, cum = 0;
        int b = 0;
        for (; b < 255; ++b) { if (cum + cnt256[b] >= r2) break; cum += cnt256[b]; }
        sh_b2 = (uint32_t)b;
    }
    __syncthreads();
    uint32_t b2 = sh_b2;
    uint32_t uthr = (a << 20) | (b1 << 8) | b2;

    double g2 = 0.0;
    for (int i = tid; i < 256; i += K4T) if (i > (int)b2) g2 += sum256[i];

    double tot = blockReduceSum(g + g2 + sMid);
    if (tid == 0) {
        tot += (double)cnt256[b2] * (double)u2f(uthr);
        double gtBase = flagOk[row] ? rowSumGtWin[row] : rowSumGtFB[row];
        double den = gtBase + tot;
        double num = rowSum[row];
        double sc  = (den == 0.0) ? 0.0 : fabs(num / den);
        scaleArr[row] = (float)sc;
        thrArr[row]   = u2f(uthr);
    }
}

// K5: out = (x < thr) ? 0 : x * scale. NT stores keep x resident in cache.
__global__ void __launch_bounds__(THREADS) k5_out(
    const float* __restrict__ x, float* __restrict__ out,
    const float* __restrict__ scaleArr, const float* __restrict__ thrArr,
    int blocksPerRow, int n) {
    int row   = blockIdx.x / blocksPerRow;
    int chunk = blockIdx.x % blocksPerRow;
    float sc = scaleArr[row];
    float th = thrArr[row];
    size_t base = (size_t)row * n + (size_t)chunk * EPB;
    const float4* p = (const float4*)(x + base);
    vfloat4* o = (vfloat4*)(out + base);
    #pragma unroll 4
    for (int it = 0; it < ITERS; ++it) {
        float4 v = p[it * THREADS + threadIdx.x];
        vfloat4 w;
        w.x = (v.x < th) ? 0.0f : v.x * sc;
        w.y = (v.y < th) ? 0.0f : v.y * sc;
        w.z = (v.z < th) ? 0.0f : v.z * sc;
        w.w = (v.w < th) ? 0.0f : v.w * sc;
        __builtin_nontemporal_store(w, &o[it * THREADS + threadIdx.x]);
    }
}

extern "C" void kernel_launch(void* const* d_in, const int* in_sizes, int n_in,
                              void* d_out, int out_size, void* d_ws, size_t ws_size,
                              hipStream_t stream) {
    const float* x     = (const float*)d_in[0];
    const float* probs = (const float*)d_in[1];
    float* out = (float*)d_out;

    int B = in_sizes[1];                     // 16
    long long total = in_sizes[0];           // 33554432
    int n = (int)(total / B);                // 2097152 per row
    int blocksPerRow = n / EPB;              // 32

    // workspace layout
    uint8_t* ws = (uint8_t*)d_ws;
    size_t off = 0;
    uint32_t* ghist    = (uint32_t*)(ws + off); off += (size_t)B * NBINS * 4;
    double* rowSum     = (double*)(ws + off);   off += (size_t)B * 8;
    double* rowSumGtW  = (double*)(ws + off);   off += (size_t)B * 8;
    double* rowSumGtFB = (double*)(ws + off);   off += (size_t)B * 8;
    uint32_t* aStar    = (uint32_t*)(ws + off); off += (size_t)B * 4;
    uint32_t* rankW    = (uint32_t*)(ws + off); off += (size_t)B * 4;
    uint32_t* winLo    = (uint32_t*)(ws + off); off += (size_t)B * 4;
    uint32_t* winHi    = (uint32_t*)(ws + off); off += (size_t)B * 4;
    uint32_t* flagOk   = (uint32_t*)(ws + off); off += (size_t)B * 4;
    uint32_t* candCnt  = (uint32_t*)(ws + off); off += (size_t)B * CNT_STRIDE * 4;
    float* scaleArr    = (float*)(ws + off);    off += (size_t)B * 4;
    float* thrArr      = (float*)(ws + off);    off += (size_t)B * 4;
    off = (off + 255) & ~(size_t)255;
    size_t zeroBytes = off;
    size_t remain = (ws_size > off) ? (ws_size - off) : 0;
    int cap = (int)(remain / ((size_t)B * 4));
    if (cap > (1 << 20)) cap = (1 << 20);
    if (cap < 1) cap = 1;
    uint32_t* cand = (uint32_t*)(ws + off);

    int n16 = (int)(zeroBytes / 16);
    k0_zero    <<<128,              THREADS, 0, stream>>>((uint4*)d_ws, n16);
    kS_window  <<<B,                THREADS, 0, stream>>>(x, probs, winLo, winHi, n);
    k13_main   <<<B * blocksPerRow, THREADS, 0, stream>>>(x, winLo, winHi, ghist, rowSum,
                                                          rowSumGtW, cand, candCnt,
                                                          blocksPerRow, cap, n);
    k2_select  <<<B,                THREADS, 0, stream>>>(ghist, probs, aStar, rankW,
                                                          candCnt, winLo, winHi, flagOk, cap, n);
    k3_fallback<<<B * blocksPerRow, THREADS, 0, stream>>>(x, aStar, flagOk, cand, candCnt,
                                                          rowSumGtFB, blocksPerRow, cap, n);
    k4_final   <<<B,                K4T,     0, stream>>>(cand, candCnt, aStar, rankW,
                                                          rowSum, rowSumGtW, rowSumGtFB, flagOk,
                                                          scaleArr, thrArr, cap);
    k5_out     <<<B * blocksPerRow, THREADS, 0, stream>>>(x, out, scaleArr, thrArr,
                                                          blocksPerRow, n);
}

// Round 9
// 230.337 us; speedup vs baseline: 1.1215x; 1.1215x over previous
//
#include <hip/hip_runtime.h>
#include <stdint.h>

#define THREADS 256
#define EPB     65536            // elements per block for streaming kernels
#define NBINS   4096             // 12-bit coarse histogram
#define ITERS   (EPB / 4 / THREADS)
#define CNT_STRIDE 16            // counters padded: one 64B cacheline per row
#define LDSCAP  8192             // per-block LDS candidate buffer (32 KB)
#define K4T     1024             // k4b block size (16 waves)
#define K4LDS   16384            // k4b LDS candidate stage (64 KB)
#define FBLK    16               // k4a blocks per row
#define CAP2    262144           // cand2 per-row capacity
#define SAMPLE_STRIDE 64         // float4 stride for sampling (1/64 of data)
#define SMARGIN 600              // sample-rank margin (~6.6 sigma)

typedef float vfloat4 __attribute__((ext_vector_type(4)));  // native vec for NT store

// Order-preserving float -> uint transform (uint compare == float compare)
__device__ __forceinline__ uint32_t f2u(float f) {
    uint32_t b = __float_as_uint(f);
    return (b & 0x80000000u) ? ~b : (b | 0x80000000u);
}
__device__ __forceinline__ float u2f(uint32_t u) {
    uint32_t b = (u & 0x80000000u) ? (u & 0x7FFFFFFFu) : ~u;
    return __uint_as_float(b);
}

// Block-wide double sum; valid on thread 0. Any blockDim multiple of 64.
// NOTE: caller must __syncthreads() between consecutive calls (shared wsum reuse).
__device__ __forceinline__ double blockReduceSum(double v) {
    for (int off = 32; off > 0; off >>= 1) v += __shfl_down(v, off, 64);
    __shared__ double wsum[16];
    int lane = threadIdx.x & 63, wid = threadIdx.x >> 6;
    if (lane == 0) wsum[wid] = v;
    __syncthreads();
    double r = 0.0;
    if (threadIdx.x == 0) {
        int nw = (int)(blockDim.x >> 6);
        for (int i = 0; i < nw; ++i) r += wsum[i];
    }
    return r;
}

// K0: zero the accumulator region of the workspace
__global__ void __launch_bounds__(THREADS) k0_zero(uint4* __restrict__ p, int n16) {
    int idx = blockIdx.x * THREADS + threadIdx.x;
    int stride = gridDim.x * THREADS;
    uint4 z = {0u, 0u, 0u, 0u};
    for (int i = idx; i < n16; i += stride) p[i] = z;
}

// KS: sampled (1/64) per-row coarse histogram -> window [lo,hi] of coarse bins
//     guaranteed (w.h.p.; verified exactly in k2) to contain a*.
__global__ void __launch_bounds__(THREADS) kS_window(
    const float* __restrict__ x, const float* __restrict__ probs,
    uint32_t* __restrict__ winLo, uint32_t* __restrict__ winHi, int n) {
    int row = blockIdx.x;
    __shared__ uint32_t hist[NBINS];
    __shared__ uint32_t part[THREADS];
    for (int i = threadIdx.x; i < NBINS; i += THREADS) hist[i] = 0;
    __syncthreads();
    const float4* p = (const float4*)(x + (size_t)row * n);
    int nf4 = n / 4;
    int ns4 = nf4 / SAMPLE_STRIDE;                 // sampled float4 per row
    for (int i = threadIdx.x; i < ns4; i += THREADS) {
        float4 v = p[(size_t)i * SAMPLE_STRIDE];
        atomicAdd(&hist[f2u(v.x) >> 20], 1u);
        atomicAdd(&hist[f2u(v.y) >> 20], 1u);
        atomicAdd(&hist[f2u(v.z) >> 20], 1u);
        atomicAdd(&hist[f2u(v.w) >> 20], 1u);
    }
    __syncthreads();
    uint32_t sLoc = 0;
    for (int j = 0; j < NBINS / THREADS; ++j) sLoc += hist[threadIdx.x * (NBINS / THREADS) + j];
    part[threadIdx.x] = sLoc;
    __syncthreads();
    if (threadIdx.x == 0) {
        long long nS = (long long)ns4 * 4;
        float pr = probs[row];
        float t = ceilf((float)n * pr);
        long long idx = (long long)t - 1; if (idx < 0) idx = 0;
        unsigned long long k = (unsigned long long)idx + 1;    // 1-indexed true rank
        long long rS = (long long)((k * (unsigned long long)nS) / (unsigned long long)n);
        long long loT = rS - SMARGIN;
        long long hiT = rS + SMARGIN;
        int lo, hi;
        if (loT <= 0) lo = 0;
        else {
            uint32_t T = (uint32_t)loT, cum = 0; int ch = 0;
            for (; ch < THREADS - 1; ++ch) { if (cum + part[ch] >= T) break; cum += part[ch]; }
            int b = ch * (NBINS / THREADS);
            for (;; ++b) { uint32_t cb = hist[b]; if (cum + cb >= T || b == NBINS - 1) break; cum += cb; }
            lo = b;
        }
        if (hiT >= nS) hi = NBINS - 1;
        else {
            uint32_t T = (uint32_t)hiT, cum = 0; int ch = 0;
            for (; ch < THREADS - 1; ++ch) { if (cum + part[ch] >= T) break; cum += part[ch]; }
            int b = ch * (NBINS / THREADS);
            for (;; ++b) { uint32_t cb = hist[b]; if (cum + cb >= T || b == NBINS - 1) break; cum += cb; }
            hi = b;
        }
        if (hi < lo) hi = lo;
        winLo[row] = (uint32_t)lo;
        winHi[row] = (uint32_t)hi;
    }
}

// K13: ONE full pass over x: exact coarse hist + rowSum + sumGt(bins>hi) +
//      candidate compaction for coarse bins in [lo,hi] (LDS-staged).
__global__ void __launch_bounds__(THREADS) k13_main(
    const float* __restrict__ x, const uint32_t* __restrict__ winLo,
    const uint32_t* __restrict__ winHi, uint32_t* __restrict__ ghist,
    double* __restrict__ rowSum, double* __restrict__ rowSumGtWin,
    uint32_t* __restrict__ cand, uint32_t* __restrict__ candCount,
    int blocksPerRow, int cap, int n) {
    __shared__ uint32_t hist[NBINS];
    __shared__ uint32_t lbuf[LDSCAP];
    __shared__ uint32_t lcnt, gbase;
    for (int i = threadIdx.x; i < NBINS; i += THREADS) hist[i] = 0;
    if (threadIdx.x == 0) lcnt = 0;
    __syncthreads();

    int row   = blockIdx.x / blocksPerRow;
    int chunk = blockIdx.x % blocksPerRow;
    uint32_t lo = winLo[row], hi = winHi[row];
    uint32_t* cl = cand + (size_t)row * cap;
    uint32_t* cc = candCount + (size_t)row * CNT_STRIDE;
    const float4* p = (const float4*)(x + (size_t)row * n + (size_t)chunk * EPB);

    double s = 0.0, sGt = 0.0;
    #pragma unroll 4
    for (int it = 0; it < ITERS; ++it) {
        float4 v = p[it * THREADS + threadIdx.x];
        float vals[4] = {v.x, v.y, v.z, v.w};
        #pragma unroll
        for (int j = 0; j < 4; ++j) {
            uint32_t u = f2u(vals[j]);
            uint32_t b = u >> 20;
            atomicAdd(&hist[b], 1u);
            s += (double)vals[j];
            if (b > hi) sGt += (double)vals[j];
            else if (b >= lo) {
                uint32_t pos = atomicAdd(&lcnt, 1u);
                if (pos < LDSCAP) lbuf[pos] = u;
                else { uint32_t g = atomicAdd(cc, 1u); if ((int)g < cap) cl[g] = u; }
            }
        }
    }
    __syncthreads();
    uint32_t* gh = ghist + (size_t)row * NBINS;
    for (int i = threadIdx.x; i < NBINS; i += THREADS) {
        uint32_t hv = hist[i];
        if (hv) atomicAdd(&gh[i], hv);
    }
    uint32_t cnt = (lcnt < LDSCAP) ? lcnt : LDSCAP;
    if (threadIdx.x == 0) gbase = atomicAdd(cc, cnt);
    __syncthreads();
    uint32_t base = gbase;
    for (uint32_t i = threadIdx.x; i < cnt; i += THREADS) {
        uint32_t g = base + i;
        if ((int)g < cap) cl[g] = lbuf[i];
    }
    double bs = blockReduceSum(s);
    if (threadIdx.x == 0) atomicAdd(&rowSum[row], bs);
    __syncthreads();                                  // wsum reuse hazard
    double bg = blockReduceSum(sGt);
    if (threadIdx.x == 0) atomicAdd(&rowSumGtWin[row], bg);
}

// K2: exact scan -> a*, rank-within-a*; verify window & candidate capacity
__global__ void __launch_bounds__(THREADS) k2_select(
    const uint32_t* __restrict__ ghist, const float* __restrict__ probs,
    uint32_t* __restrict__ aStar, uint32_t* __restrict__ rankW,
    uint32_t* __restrict__ candCnt, const uint32_t* __restrict__ winLo,
    const uint32_t* __restrict__ winHi, uint32_t* __restrict__ flagOk,
    int cap, int n) {
    int row = blockIdx.x;
    const uint32_t* h = ghist + (size_t)row * NBINS;
    __shared__ uint32_t part[THREADS];
    uint32_t s = 0;
    #pragma unroll
    for (int i = 0; i < NBINS / THREADS; ++i) s += h[threadIdx.x * (NBINS / THREADS) + i];
    part[threadIdx.x] = s;
    __syncthreads();
    if (threadIdx.x == 0) {
        float p = probs[row];
        float t = ceilf((float)n * p);
        long long idx = (long long)t - 1;
        if (idx < 0) idx = 0;
        uint32_t k = (uint32_t)idx + 1;
        uint32_t cum = 0;
        int chunk = 0;
        for (; chunk < THREADS - 1; ++chunk) {
            if (cum + part[chunk] >= k) break;
            cum += part[chunk];
        }
        int bin = chunk * (NBINS / THREADS);
        for (;; ++bin) {
            uint32_t c = h[bin];
            if (cum + c >= k || bin == NBINS - 1) break;
            cum += c;
        }
        aStar[row] = (uint32_t)bin;
        rankW[row] = k - cum;
        uint32_t ccv = candCnt[(size_t)row * CNT_STRIDE];
        int ok = (bin >= (int)winLo[row] && bin <= (int)winHi[row] &&
                  ccv <= (uint32_t)cap) ? 1 : 0;
        flagOk[row] = (uint32_t)ok;
        if (!ok) candCnt[(size_t)row * CNT_STRIDE] = 0;   // fallback refills
    }
}

// K3FB: classic candidate pass — runs only if the window missed (early exit).
__global__ void __launch_bounds__(THREADS) k3_fallback(
    const float* __restrict__ x, const uint32_t* __restrict__ aStar,
    const uint32_t* __restrict__ flagOk,
    uint32_t* __restrict__ cand, uint32_t* __restrict__ candCount,
    double* __restrict__ rowSumGtFB, int blocksPerRow, int cap, int n) {
    int row   = blockIdx.x / blocksPerRow;
    if (flagOk[row]) return;
    __shared__ uint32_t lbuf[LDSCAP];
    __shared__ uint32_t lcnt, gbase;
    if (threadIdx.x == 0) lcnt = 0;
    __syncthreads();
    int chunk = blockIdx.x % blocksPerRow;
    uint32_t a = aStar[row];
    uint32_t* cl = cand + (size_t)row * cap;
    uint32_t* cc = candCount + (size_t)row * CNT_STRIDE;
    const float4* p = (const float4*)(x + (size_t)row * n + (size_t)chunk * EPB);

    double sg = 0.0;
    #pragma unroll 4
    for (int it = 0; it < ITERS; ++it) {
        float4 v = p[it * THREADS + threadIdx.x];
        float vals[4] = {v.x, v.y, v.z, v.w};
        #pragma unroll
        for (int j = 0; j < 4; ++j) {
            uint32_t u = f2u(vals[j]);
            uint32_t b = u >> 20;
            if (b > a) sg += (double)vals[j];
            else if (b == a) {
                uint32_t pos = atomicAdd(&lcnt, 1u);
                if (pos < LDSCAP) lbuf[pos] = u;
                else { uint32_t g = atomicAdd(cc, 1u); if ((int)g < cap) cl[g] = u; }
            }
        }
    }
    __syncthreads();
    uint32_t cnt = (lcnt < LDSCAP) ? lcnt : LDSCAP;
    if (threadIdx.x == 0) gbase = atomicAdd(cc, cnt);
    __syncthreads();
    uint32_t base = gbase;
    for (uint32_t i = threadIdx.x; i < cnt; i += THREADS) {
        uint32_t g = base + i;
        if ((int)g < cap) cl[g] = lbuf[i];
    }
    double bs = blockReduceSum(sg);
    if (threadIdx.x == 0) atomicAdd(&rowSumGtFB[row], bs);
}

// K4A: PARALLEL narrow (FBLK blocks/row): filter window candidates to cb==a*
//      into cand2 (LDS-staged, 1 global atomic/block); sum cb>a* into rowSumMid.
__global__ void __launch_bounds__(THREADS) k4a_filter(
    const uint32_t* __restrict__ cand, const uint32_t* __restrict__ candCount,
    const uint32_t* __restrict__ aStar,
    uint32_t* __restrict__ cand2, uint32_t* __restrict__ candCount2,
    double* __restrict__ rowSumMid, int cap) {
    __shared__ uint32_t lbuf[LDSCAP];
    __shared__ uint32_t lcnt, gbase;
    if (threadIdx.x == 0) lcnt = 0;
    __syncthreads();

    int row   = blockIdx.x / FBLK;
    int slice = blockIdx.x % FBLK;
    uint32_t c = candCount[(size_t)row * CNT_STRIDE];
    if (c > (uint32_t)cap) c = (uint32_t)cap;
    uint32_t a = aStar[row];
    const uint32_t* cl = cand + (size_t)row * cap;
    uint32_t* cl2 = cand2 + (size_t)row * CAP2;
    uint32_t* cc2 = candCount2 + (size_t)row * CNT_STRIDE;

    double sMid = 0.0;
    for (uint32_t i = (uint32_t)slice * THREADS + threadIdx.x; i < c;
         i += (uint32_t)FBLK * THREADS) {
        uint32_t u = cl[i];
        uint32_t cb = u >> 20;
        if (cb == a) {
            uint32_t pos = atomicAdd(&lcnt, 1u);
            if (pos < LDSCAP) lbuf[pos] = u;
            else { uint32_t g = atomicAdd(cc2, 1u); if (g < CAP2) cl2[g] = u; }
        } else if (cb > a) {
            sMid += (double)u2f(u);
        }
    }
    __syncthreads();
    uint32_t cnt = (lcnt < LDSCAP) ? lcnt : LDSCAP;
    if (threadIdx.x == 0) gbase = atomicAdd(cc2, cnt);
    __syncthreads();
    uint32_t base = gbase;
    for (uint32_t i = threadIdx.x; i < cnt; i += THREADS) {
        uint32_t g = base + i;
        if (g < CAP2) cl2[g] = lbuf[i];
    }
    double bs = blockReduceSum(sMid);
    if (threadIdx.x == 0) atomicAdd(&rowSumMid[row], bs);
}

// K4B: two-pass select over cand2 (all coarse==a*), LDS-staged.
//  Pass A: hist+sum on bits[19:8] -> b1. Pass B: low byte -> b2.
//  prefix|b1|b2 fixes all 32 bits; b2-slot elements equal the threshold.
__global__ void __launch_bounds__(K4T) k4b_final(
    const uint32_t* __restrict__ cand2, const uint32_t* __restrict__ candCount2,
    const uint32_t* __restrict__ aStar, const uint32_t* __restrict__ rankW,
    const double* __restrict__ rowSum, const double* __restrict__ rowSumGtWin,
    const double* __restrict__ rowSumGtFB, const double* __restrict__ rowSumMid,
    const uint32_t* __restrict__ flagOk,
    float* __restrict__ scaleArr, float* __restrict__ thrArr) {
    int row = blockIdx.x, tid = threadIdx.x;
    uint32_t c = candCount2[(size_t)row * CNT_STRIDE];
    if (c > (uint32_t)CAP2) c = (uint32_t)CAP2;
    const uint32_t* cl = cand2 + (size_t)row * CAP2;
    uint32_t a = aStar[row];

    __shared__ uint32_t buf[K4LDS];
    __shared__ uint32_t hcnt[4096];
    __shared__ double   hsum[4096];
    __shared__ uint32_t part1[K4T];
    __shared__ uint32_t part2[64];
    __shared__ uint32_t cnt256[256];
    __shared__ double   sum256[256];
    __shared__ uint32_t sh_b1, sh_r2, sh_b2;

    uint32_t cLds = (c < (uint32_t)K4LDS) ? c : (uint32_t)K4LDS;
    for (uint32_t i = tid; i < cLds; i += K4T) buf[i] = cl[i];

    for (int i = tid; i < 4096; i += K4T) { hcnt[i] = 0; hsum[i] = 0.0; }
    for (int i = tid; i < 256;  i += K4T) { cnt256[i] = 0; sum256[i] = 0.0; }
    __syncthreads();

    // Pass A
    for (uint32_t i = tid; i < c; i += K4T) {
        uint32_t u = (i < cLds) ? buf[i] : cl[i];
        uint32_t b = (u >> 8) & 0xFFFu;
        atomicAdd(&hcnt[b], 1u);
        atomicAdd(&hsum[b], (double)u2f(u));
    }
    __syncthreads();

    uint32_t p1 = hcnt[tid*4] + hcnt[tid*4+1] + hcnt[tid*4+2] + hcnt[tid*4+3];
    part1[tid] = p1;
    __syncthreads();
    if (tid < 64) {
        uint32_t s2 = 0;
        for (int j = 0; j < 16; ++j) s2 += part1[tid*16 + j];
        part2[tid] = s2;
    }
    __syncthreads();
    if (tid == 0) {
        uint32_t r = rankW[row], cum = 0;
        int j = 0;
        for (; j < 63; ++j) { if (cum + part2[j] >= r) break; cum += part2[j]; }
        int t = j * 16;
        for (; t < j*16 + 15; ++t) { if (cum + part1[t] >= r) break; cum += part1[t]; }
        int b = t * 4;
        for (; b < t*4 + 3; ++b) { if (cum + hcnt[b] >= r) break; cum += hcnt[b]; }
        sh_b1 = (uint32_t)b;
        sh_r2 = r - cum;
    }
    __syncthreads();
    uint32_t b1 = sh_b1;

    double g = 0.0;
    for (int i = tid; i < 4096; i += K4T) if (i > (int)b1) g += hsum[i];

    // Pass B
    for (uint32_t i = tid; i < c; i += K4T) {
        uint32_t u = (i < cLds) ? buf[i] : cl[i];
        if (((u >> 8) & 0xFFFu) == b1) {
            atomicAdd(&cnt256[u & 0xFFu], 1u);
            atomicAdd(&sum256[u & 0xFFu], (double)u2f(u));
        }
    }
    __syncthreads();
    if (tid == 0) {
        uint32_t r2 = sh_r2, cum = 0;
        int b = 0;
        for (; b < 255; ++b) { if (cum + cnt256[b] >= r2) break; cum += cnt256[b]; }
        sh_b2 = (uint32_t)b;
    }
    __syncthreads();
    uint32_t b2 = sh_b2;
    uint32_t uthr = (a << 20) | (b1 << 8) | b2;

    double g2 = 0.0;
    for (int i = tid; i < 256; i += K4T) if (i > (int)b2) g2 += sum256[i];

    double tot = blockReduceSum(g + g2);
    if (tid == 0) {
        tot += (double)cnt256[b2] * (double)u2f(uthr);
        double gtBase = flagOk[row] ? rowSumGtWin[row] : rowSumGtFB[row];
        double den = gtBase + rowSumMid[row] + tot;
        double num = rowSum[row];
        double sc  = (den == 0.0) ? 0.0 : fabs(num / den);
        scaleArr[row] = (float)sc;
        thrArr[row]   = u2f(uthr);
    }
}

// K5: out = (x < thr) ? 0 : x * scale. NT stores keep x resident in cache.
__global__ void __launch_bounds__(THREADS) k5_out(
    const float* __restrict__ x, float* __restrict__ out,
    const float* __restrict__ scaleArr, const float* __restrict__ thrArr,
    int blocksPerRow, int n) {
    int row   = blockIdx.x / blocksPerRow;
    int chunk = blockIdx.x % blocksPerRow;
    float sc = scaleArr[row];
    float th = thrArr[row];
    size_t base = (size_t)row * n + (size_t)chunk * EPB;
    const float4* p = (const float4*)(x + base);
    vfloat4* o = (vfloat4*)(out + base);
    #pragma unroll 4
    for (int it = 0; it < ITERS; ++it) {
        float4 v = p[it * THREADS + threadIdx.x];
        vfloat4 w;
        w.x = (v.x < th) ? 0.0f : v.x * sc;
        w.y = (v.y < th) ? 0.0f : v.y * sc;
        w.z = (v.z < th) ? 0.0f : v.z * sc;
        w.w = (v.w < th) ? 0.0f : v.w * sc;
        __builtin_nontemporal_store(w, &o[it * THREADS + threadIdx.x]);
    }
}

extern "C" void kernel_launch(void* const* d_in, const int* in_sizes, int n_in,
                              void* d_out, int out_size, void* d_ws, size_t ws_size,
                              hipStream_t stream) {
    const float* x     = (const float*)d_in[0];
    const float* probs = (const float*)d_in[1];
    float* out = (float*)d_out;

    int B = in_sizes[1];                     // 16
    long long total = in_sizes[0];           // 33554432
    int n = (int)(total / B);                // 2097152 per row
    int blocksPerRow = n / EPB;              // 32

    // workspace layout
    uint8_t* ws = (uint8_t*)d_ws;
    size_t off = 0;
    uint32_t* ghist    = (uint32_t*)(ws + off); off += (size_t)B * NBINS * 4;
    double* rowSum     = (double*)(ws + off);   off += (size_t)B * 8;
    double* rowSumGtW  = (double*)(ws + off);   off += (size_t)B * 8;
    double* rowSumGtFB = (double*)(ws + off);   off += (size_t)B * 8;
    double* rowSumMid  = (double*)(ws + off);   off += (size_t)B * 8;
    uint32_t* aStar    = (uint32_t*)(ws + off); off += (size_t)B * 4;
    uint32_t* rankW    = (uint32_t*)(ws + off); off += (size_t)B * 4;
    uint32_t* winLo    = (uint32_t*)(ws + off); off += (size_t)B * 4;
    uint32_t* winHi    = (uint32_t*)(ws + off); off += (size_t)B * 4;
    uint32_t* flagOk   = (uint32_t*)(ws + off); off += (size_t)B * 4;
    uint32_t* candCnt  = (uint32_t*)(ws + off); off += (size_t)B * CNT_STRIDE * 4;
    uint32_t* candCnt2 = (uint32_t*)(ws + off); off += (size_t)B * CNT_STRIDE * 4;
    float* scaleArr    = (float*)(ws + off);    off += (size_t)B * 4;
    float* thrArr      = (float*)(ws + off);    off += (size_t)B * 4;
    off = (off + 255) & ~(size_t)255;
    size_t zeroBytes = off;

    uint32_t* cand2 = (uint32_t*)(ws + off);    off += (size_t)B * CAP2 * 4;
    size_t remain = (ws_size > off) ? (ws_size - off) : 0;
    int cap = (int)(remain / ((size_t)B * 4));
    if (cap > (1 << 20)) cap = (1 << 20);
    if (cap < 1) cap = 1;
    uint32_t* cand = (uint32_t*)(ws + off);

    int n16 = (int)(zeroBytes / 16);
    k0_zero    <<<128,              THREADS, 0, stream>>>((uint4*)d_ws, n16);
    kS_window  <<<B,                THREADS, 0, stream>>>(x, probs, winLo, winHi, n);
    k13_main   <<<B * blocksPerRow, THREADS, 0, stream>>>(x, winLo, winHi, ghist, rowSum,
                                                          rowSumGtW, cand, candCnt,
                                                          blocksPerRow, cap, n);
    k2_select  <<<B,                THREADS, 0, stream>>>(ghist, probs, aStar, rankW,
                                                          candCnt, winLo, winHi, flagOk, cap, n);
    k3_fallback<<<B * blocksPerRow, THREADS, 0, stream>>>(x, aStar, flagOk, cand, candCnt,
                                                          rowSumGtFB, blocksPerRow, cap, n);
    k4a_filter <<<B * FBLK,         THREADS, 0, stream>>>(cand, candCnt, aStar, cand2,
                                                          candCnt2, rowSumMid, cap);
    k4b_final  <<<B,                K4T,     0, stream>>>(cand2, candCnt2, aStar, rankW,
                                                          rowSum, rowSumGtW, rowSumGtFB,
                                                          rowSumMid, flagOk,
                                                          scaleArr, thrArr);
    k5_out     <<<B * blocksPerRow, THREADS, 0, stream>>>(x, out, scaleArr, thrArr,
                                                          blocksPerRow, n);
}

// Round 11
// 188.500 us; speedup vs baseline: 1.3704x; 1.2219x over previous
//
#include <hip/hip_runtime.h>
#include <stdint.h>

#define THREADS 256
#define EPB     65536            // elements per block for streaming kernels
#define NBINS   4096             // 12-bit coarse histogram
#define ITERS   (EPB / 4 / THREADS)  // 64 float4 iterations per thread
#define CNT_STRIDE 16            // candCnt padded: one 64B cacheline per row
#define LDSCAP  8192             // per-block LDS candidate buffer in k3 (32 KB)
#define K4T     1024             // k4 block size (16 waves)

typedef float vfloat4 __attribute__((ext_vector_type(4)));  // native vec for NT store

// Order-preserving float -> uint transform (uint compare == float compare)
__device__ __forceinline__ uint32_t f2u(float f) {
    uint32_t b = __float_as_uint(f);
    return (b & 0x80000000u) ? ~b : (b | 0x80000000u);
}
__device__ __forceinline__ float u2f(uint32_t u) {
    uint32_t b = (u & 0x80000000u) ? (u & 0x7FFFFFFFu) : ~u;
    return __uint_as_float(b);
}

// Block-wide double sum; valid on thread 0. Works for any blockDim multiple of 64.
__device__ __forceinline__ double blockReduceSum(double v) {
    for (int off = 32; off > 0; off >>= 1) v += __shfl_down(v, off, 64);
    __shared__ double wsum[16];
    int lane = threadIdx.x & 63, wid = threadIdx.x >> 6;
    if (lane == 0) wsum[wid] = v;
    __syncthreads();
    double r = 0.0;
    if (threadIdx.x == 0) {
        int nw = (int)(blockDim.x >> 6);
        for (int i = 0; i < nw; ++i) r += wsum[i];
    }
    return r;
}

// K0: zero the accumulator region of the workspace
__global__ void __launch_bounds__(THREADS) k0_zero(uint4* __restrict__ p, int n16) {
    int idx = blockIdx.x * THREADS + threadIdx.x;
    int stride = gridDim.x * THREADS;
    uint4 z = {0u, 0u, 0u, 0u};
    for (int i = idx; i < n16; i += stride) p[i] = z;
}

// K1: coarse 12-bit histogram (LDS-privatized) + per-row double sum
__global__ void __launch_bounds__(THREADS) k1_hist(
    const float* __restrict__ x, uint32_t* __restrict__ ghist,
    double* __restrict__ rowSum, int blocksPerRow, int n) {
    __shared__ uint32_t hist[NBINS];
    for (int i = threadIdx.x; i < NBINS; i += THREADS) hist[i] = 0;
    __syncthreads();

    int row   = blockIdx.x / blocksPerRow;
    int chunk = blockIdx.x % blocksPerRow;
    const float4* p = (const float4*)(x + (size_t)row * n + (size_t)chunk * EPB);

    double s = 0.0;
    #pragma unroll 4
    for (int it = 0; it < ITERS; ++it) {
        float4 v = p[it * THREADS + threadIdx.x];
        s += (double)v.x + (double)v.y + (double)v.z + (double)v.w;
        atomicAdd(&hist[f2u(v.x) >> 20], 1u);
        atomicAdd(&hist[f2u(v.y) >> 20], 1u);
        atomicAdd(&hist[f2u(v.z) >> 20], 1u);
        atomicAdd(&hist[f2u(v.w) >> 20], 1u);
    }
    __syncthreads();

    uint32_t* gh = ghist + (size_t)row * NBINS;
    for (int i = threadIdx.x; i < NBINS; i += THREADS) {
        uint32_t c = hist[i];
        if (c) atomicAdd(&gh[i], c);
    }
    double bs = blockReduceSum(s);
    if (threadIdx.x == 0) atomicAdd(&rowSum[row], bs);
}

// K2: per-row scan of coarse histogram -> coarse bin a*, residual rank r
__global__ void __launch_bounds__(THREADS) k2_select(
    const uint32_t* __restrict__ ghist, const float* __restrict__ probs,
    uint32_t* __restrict__ aStar, uint32_t* __restrict__ rankW, int n) {
    int row = blockIdx.x;
    const uint32_t* h = ghist + (size_t)row * NBINS;
    __shared__ uint32_t part[THREADS];
    uint32_t s = 0;
    #pragma unroll
    for (int i = 0; i < NBINS / THREADS; ++i) s += h[threadIdx.x * (NBINS / THREADS) + i];
    part[threadIdx.x] = s;
    __syncthreads();
    if (threadIdx.x == 0) {
        float p = probs[row];
        float t = ceilf((float)n * p);          // matches jnp: ceil(f32(n) * prob)
        long long idx = (long long)t - 1;
        if (idx < 0) idx = 0;
        uint32_t k = (uint32_t)idx + 1;         // 1-indexed rank, <= n
        uint32_t cum = 0;
        int chunk = 0;
        for (; chunk < THREADS - 1; ++chunk) {
            if (cum + part[chunk] >= k) break;
            cum += part[chunk];
        }
        int bin = chunk * (NBINS / THREADS);
        for (;; ++bin) {
            uint32_t c = h[bin];
            if (cum + c >= k || bin == NBINS - 1) break;
            cum += c;
        }
        aStar[row] = (uint32_t)bin;
        rankW[row] = k - cum;                   // 1-indexed rank within bin
    }
}

// K3: compact candidates (coarse bin == a*) via LDS staging (1 global atomic
//     per block), double-sum elements in bins > a*
__global__ void __launch_bounds__(THREADS) k3_cand(
    const float* __restrict__ x, const uint32_t* __restrict__ aStar,
    uint32_t* __restrict__ cand, uint32_t* __restrict__ candCount,
    double* __restrict__ rowSumGt, int blocksPerRow, int cap, int n) {
    __shared__ uint32_t lbuf[LDSCAP];
    __shared__ uint32_t lcnt;
    __shared__ uint32_t gbase;
    if (threadIdx.x == 0) lcnt = 0;
    __syncthreads();

    int row   = blockIdx.x / blocksPerRow;
    int chunk = blockIdx.x % blocksPerRow;
    uint32_t a = aStar[row];
    uint32_t* cl = cand + (size_t)row * cap;
    uint32_t* cc = candCount + (size_t)row * CNT_STRIDE;
    const float4* p = (const float4*)(x + (size_t)row * n + (size_t)chunk * EPB);

    double s = 0.0;
    #pragma unroll 4
    for (int it = 0; it < ITERS; ++it) {
        float4 v = p[it * THREADS + threadIdx.x];
        float vals[4] = {v.x, v.y, v.z, v.w};
        #pragma unroll
        for (int j = 0; j < 4; ++j) {
            uint32_t u = f2u(vals[j]);
            uint32_t b = u >> 20;
            if (b > a) s += (double)vals[j];
            else if (b == a) {
                uint32_t pos = atomicAdd(&lcnt, 1u);   // LDS atomic, cheap
                if (pos < LDSCAP) lbuf[pos] = u;
                else {                                  // rare spill path
                    uint32_t g = atomicAdd(cc, 1u);
                    if ((int)g < cap) cl[g] = u;
                }
            }
        }
    }
    __syncthreads();
    uint32_t cnt = (lcnt < LDSCAP) ? lcnt : LDSCAP;
    if (threadIdx.x == 0) gbase = atomicAdd(cc, cnt);   // ONE global atomic/block
    __syncthreads();
    uint32_t base = gbase;
    for (uint32_t i = threadIdx.x; i < cnt; i += THREADS) {
        uint32_t g = base + i;
        if ((int)g < cap) cl[g] = lbuf[i];
    }
    double bs = blockReduceSum(s);
    if (threadIdx.x == 0) atomicAdd(&rowSumGt[row], bs);
}

// K4: two-pass select with per-bin double sums.
//  Pass A: 4096-bin hist+sum over bits[19:8] -> b1; sum of bins>b1 is the bulk
//          of the kept-sum.
//  Pass B: 256-bin hist+sum over bits[7:0] among bin==b1 -> b2. prefix|b1|b2
//          fixes ALL 32 bits, so the b2 slot elements all equal the threshold:
//          cnt256[b2]*u2f(uthr) completes the kept-sum. No further passes.
__global__ void __launch_bounds__(K4T) k4_final(
    const uint32_t* __restrict__ cand, const uint32_t* __restrict__ candCount,
    const uint32_t* __restrict__ aStar, const uint32_t* __restrict__ rankW,
    const double* __restrict__ rowSum, const double* __restrict__ rowSumGt,
    float* __restrict__ scaleArr, float* __restrict__ thrArr, int cap) {
    int row = blockIdx.x, tid = threadIdx.x;
    uint32_t c = candCount[(size_t)row * CNT_STRIDE];
    if (c > (uint32_t)cap) c = (uint32_t)cap;
    const uint32_t* cl = cand + (size_t)row * cap;

    __shared__ uint32_t hcnt[4096];
    __shared__ double   hsum[4096];
    __shared__ uint32_t part1[K4T];
    __shared__ uint32_t part2[64];
    __shared__ uint32_t cnt256[256];
    __shared__ double   sum256[256];
    __shared__ uint32_t sh_b1, sh_r2, sh_b2;

    for (int i = tid; i < 4096; i += K4T) { hcnt[i] = 0; hsum[i] = 0.0; }
    for (int i = tid; i < 256;  i += K4T) { cnt256[i] = 0; sum256[i] = 0.0; }
    __syncthreads();

    // Pass A
    for (uint32_t i = tid; i < c; i += K4T) {
        uint32_t u = cl[i];
        uint32_t b = (u >> 8) & 0xFFFu;
        atomicAdd(&hcnt[b], 1u);
        atomicAdd(&hsum[b], (double)u2f(u));
    }
    __syncthreads();

    // hierarchical rank scan: 1024 partials of 4 bins, 64 super-partials of 16
    uint32_t p1 = hcnt[tid*4] + hcnt[tid*4+1] + hcnt[tid*4+2] + hcnt[tid*4+3];
    part1[tid] = p1;
    __syncthreads();
    if (tid < 64) {
        uint32_t s2 = 0;
        for (int j = 0; j < 16; ++j) s2 += part1[tid*16 + j];
        part2[tid] = s2;
    }
    __syncthreads();
    if (tid == 0) {
        uint32_t r = rankW[row];              // 1-indexed within coarse bin
        uint32_t cum = 0;
        int j = 0;
        for (; j < 63; ++j) { if (cum + part2[j] >= r) break; cum += part2[j]; }
        int t = j * 16;
        for (; t < j*16 + 15; ++t) { if (cum + part1[t] >= r) break; cum += part1[t]; }
        int b = t * 4;
        for (; b < t*4 + 3; ++b) { if (cum + hcnt[b] >= r) break; cum += hcnt[b]; }
        sh_b1 = (uint32_t)b;
        sh_r2 = r - cum;                      // 1-indexed within b1
    }
    __syncthreads();
    uint32_t b1 = sh_b1;

    // kept-sum contribution from bins > b1
    double g = 0.0;
    for (int i = tid; i < 4096; i += K4T) if (i > (int)b1) g += hsum[i];

    // Pass B: low-byte hist+sum among bin==b1
    for (uint32_t i = tid; i < c; i += K4T) {
        uint32_t u = cl[i];
        if (((u >> 8) & 0xFFFu) == b1) {
            atomicAdd(&cnt256[u & 0xFFu], 1u);
            atomicAdd(&sum256[u & 0xFFu], (double)u2f(u));
        }
    }
    __syncthreads();
    if (tid == 0) {
        uint32_t r2 = sh_r2, cum = 0;
        int b = 0;
        for (; b < 255; ++b) { if (cum + cnt256[b] >= r2) break; cum += cnt256[b]; }
        sh_b2 = (uint32_t)b;
    }
    __syncthreads();
    uint32_t b2 = sh_b2;
    uint32_t uthr = (aStar[row] << 20) | (b1 << 8) | b2;

    double g2 = 0.0;
    for (int i = tid; i < 256; i += K4T) if (i > (int)b2) g2 += sum256[i];

    double tot = blockReduceSum(g + g2);
    if (tid == 0) {
        // elements in the b2 slot are bit-identical to the threshold
        tot += (double)cnt256[b2] * (double)u2f(uthr);
        double den = rowSumGt[row] + tot;
        double num = rowSum[row];
        double sc  = (den == 0.0) ? 0.0 : fabs(num / den);
        scaleArr[row] = (float)sc;
        thrArr[row]   = u2f(uthr);
    }
}

// K5: out = (x < thr) ? 0 : x * scale. Non-temporal stores keep x resident in
//     L2/L3 (x + out together exceed the 256MB L3; out is never re-read).
__global__ void __launch_bounds__(THREADS) k5_out(
    const float* __restrict__ x, float* __restrict__ out,
    const float* __restrict__ scaleArr, const float* __restrict__ thrArr,
    int blocksPerRow, int n) {
    int row   = blockIdx.x / blocksPerRow;
    int chunk = blockIdx.x % blocksPerRow;
    float sc = scaleArr[row];
    float th = thrArr[row];
    size_t base = (size_t)row * n + (size_t)chunk * EPB;
    const float4* p = (const float4*)(x + base);
    vfloat4* o = (vfloat4*)(out + base);
    #pragma unroll 4
    for (int it = 0; it < ITERS; ++it) {
        float4 v = p[it * THREADS + threadIdx.x];
        vfloat4 w;
        w.x = (v.x < th) ? 0.0f : v.x * sc;
        w.y = (v.y < th) ? 0.0f : v.y * sc;
        w.z = (v.z < th) ? 0.0f : v.z * sc;
        w.w = (v.w < th) ? 0.0f : v.w * sc;
        __builtin_nontemporal_store(w, &o[it * THREADS + threadIdx.x]);
    }
}

extern "C" void kernel_launch(void* const* d_in, const int* in_sizes, int n_in,
                              void* d_out, int out_size, void* d_ws, size_t ws_size,
                              hipStream_t stream) {
    const float* x     = (const float*)d_in[0];
    const float* probs = (const float*)d_in[1];
    float* out = (float*)d_out;

    int B = in_sizes[1];                     // 16
    long long total = in_sizes[0];           // 33554432
    int n = (int)(total / B);                // 2097152 per row
    int blocksPerRow = n / EPB;              // 32

    // workspace layout
    uint8_t* ws = (uint8_t*)d_ws;
    size_t off = 0;
    uint32_t* ghist = (uint32_t*)(ws + off); off += (size_t)B * NBINS * 4;
    double* rowSum    = (double*)(ws + off); off += (size_t)B * 8;
    double* rowSumGt  = (double*)(ws + off); off += (size_t)B * 8;
    uint32_t* aStar   = (uint32_t*)(ws + off); off += (size_t)B * 4;
    uint32_t* rankW   = (uint32_t*)(ws + off); off += (size_t)B * 4;
    uint32_t* candCnt = (uint32_t*)(ws + off); off += (size_t)B * CNT_STRIDE * 4;
    float* scaleArr   = (float*)(ws + off); off += (size_t)B * 4;
    float* thrArr     = (float*)(ws + off); off += (size_t)B * 4;
    off = (off + 255) & ~(size_t)255;
    size_t zeroBytes = off;
    size_t remain = (ws_size > off) ? (ws_size - off) : 0;
    int cap = (int)(remain / ((size_t)B * 4));
    if (cap > 262144) cap = 262144;
    if (cap < 1) cap = 1;
    uint32_t* cand = (uint32_t*)(ws + off);

    // zero accumulators every launch with our own kernel
    int n16 = (int)(zeroBytes / 16);
    k0_zero  <<<128,              THREADS, 0, stream>>>((uint4*)d_ws, n16);

    k1_hist  <<<B * blocksPerRow, THREADS, 0, stream>>>(x, ghist, rowSum, blocksPerRow, n);
    k2_select<<<B,                THREADS, 0, stream>>>(ghist, probs, aStar, rankW, n);
    k3_cand  <<<B * blocksPerRow, THREADS, 0, stream>>>(x, aStar, cand, candCnt, rowSumGt,
                                                        blocksPerRow, cap, n);
    k4_final <<<B,                K4T,     0, stream>>>(cand, candCnt, aStar, rankW,
                                                        rowSum, rowSumGt, scaleArr, thrArr, cap);
    k5_out   <<<B * blocksPerRow, THREADS, 0, stream>>>(x, out, scaleArr, thrArr, blocksPerRow, n);
}

// Round 12
// 163.794 us; speedup vs baseline: 1.5771x; 1.1508x over previous
//
#include <hip/hip_runtime.h>
#include <stdint.h>

#define THREADS 256
#define EPB     32768            // elements per block (1024 blocks = 4/CU for TLP)
#define NBINS   4096             // 12-bit coarse histogram
#define ITERS   (EPB / 4 / THREADS)  // 32 float4 iterations per thread
#define CNT_STRIDE 16            // candCnt padded: one 64B cacheline per row
#define LDSCAP  8192             // per-block LDS candidate buffer in k3 (32 KB)
#define K4T     1024             // k4 block size (16 waves)

typedef float vfloat4 __attribute__((ext_vector_type(4)));  // native vec for NT store

// Order-preserving float -> uint transform (uint compare == float compare)
__device__ __forceinline__ uint32_t f2u(float f) {
    uint32_t b = __float_as_uint(f);
    return (b & 0x80000000u) ? ~b : (b | 0x80000000u);
}
__device__ __forceinline__ float u2f(uint32_t u) {
    uint32_t b = (u & 0x80000000u) ? (u & 0x7FFFFFFFu) : ~u;
    return __uint_as_float(b);
}

// Block-wide double sum; valid on thread 0. Works for any blockDim multiple of 64.
__device__ __forceinline__ double blockReduceSum(double v) {
    for (int off = 32; off > 0; off >>= 1) v += __shfl_down(v, off, 64);
    __shared__ double wsum[16];
    int lane = threadIdx.x & 63, wid = threadIdx.x >> 6;
    if (lane == 0) wsum[wid] = v;
    __syncthreads();
    double r = 0.0;
    if (threadIdx.x == 0) {
        int nw = (int)(blockDim.x >> 6);
        for (int i = 0; i < nw; ++i) r += wsum[i];
    }
    return r;
}

// K0: zero the accumulator region of the workspace
__global__ void __launch_bounds__(THREADS) k0_zero(uint4* __restrict__ p, int n16) {
    int idx = blockIdx.x * THREADS + threadIdx.x;
    int stride = gridDim.x * THREADS;
    uint4 z = {0u, 0u, 0u, 0u};
    for (int i = idx; i < n16; i += stride) p[i] = z;
}

// K1: coarse 12-bit histogram (LDS-privatized) + per-row double sum
__global__ void __launch_bounds__(THREADS) k1_hist(
    const float* __restrict__ x, uint32_t* __restrict__ ghist,
    double* __restrict__ rowSum, int blocksPerRow, int n) {
    __shared__ uint32_t hist[NBINS];
    for (int i = threadIdx.x; i < NBINS; i += THREADS) hist[i] = 0;
    __syncthreads();

    int row   = blockIdx.x / blocksPerRow;
    int chunk = blockIdx.x % blocksPerRow;
    const float4* p = (const float4*)(x + (size_t)row * n + (size_t)chunk * EPB);

    double s = 0.0;
    #pragma unroll 4
    for (int it = 0; it < ITERS; ++it) {
        float4 v = p[it * THREADS + threadIdx.x];
        s += (double)v.x + (double)v.y + (double)v.z + (double)v.w;
        atomicAdd(&hist[f2u(v.x) >> 20], 1u);
        atomicAdd(&hist[f2u(v.y) >> 20], 1u);
        atomicAdd(&hist[f2u(v.z) >> 20], 1u);
        atomicAdd(&hist[f2u(v.w) >> 20], 1u);
    }
    __syncthreads();

    uint32_t* gh = ghist + (size_t)row * NBINS;
    for (int i = threadIdx.x; i < NBINS; i += THREADS) {
        uint32_t c = hist[i];
        if (c) atomicAdd(&gh[i], c);
    }
    double bs = blockReduceSum(s);
    if (threadIdx.x == 0) atomicAdd(&rowSum[row], bs);
}

// K2: per-row scan of coarse histogram -> coarse bin a*, residual rank r
__global__ void __launch_bounds__(THREADS) k2_select(
    const uint32_t* __restrict__ ghist, const float* __restrict__ probs,
    uint32_t* __restrict__ aStar, uint32_t* __restrict__ rankW, int n) {
    int row = blockIdx.x;
    const uint32_t* h = ghist + (size_t)row * NBINS;
    __shared__ uint32_t part[THREADS];
    uint32_t s = 0;
    #pragma unroll
    for (int i = 0; i < NBINS / THREADS; ++i) s += h[threadIdx.x * (NBINS / THREADS) + i];
    part[threadIdx.x] = s;
    __syncthreads();
    if (threadIdx.x == 0) {
        float p = probs[row];
        float t = ceilf((float)n * p);          // matches jnp: ceil(f32(n) * prob)
        long long idx = (long long)t - 1;
        if (idx < 0) idx = 0;
        uint32_t k = (uint32_t)idx + 1;         // 1-indexed rank, <= n
        uint32_t cum = 0;
        int chunk = 0;
        for (; chunk < THREADS - 1; ++chunk) {
            if (cum + part[chunk] >= k) break;
            cum += part[chunk];
        }
        int bin = chunk * (NBINS / THREADS);
        for (;; ++bin) {
            uint32_t c = h[bin];
            if (cum + c >= k || bin == NBINS - 1) break;
            cum += c;
        }
        aStar[row] = (uint32_t)bin;
        rankW[row] = k - cum;                   // 1-indexed rank within bin
    }
}

// K3: compact candidates (coarse bin == a*) via LDS staging (1 global atomic
//     per block), double-sum elements in bins > a*
__global__ void __launch_bounds__(THREADS) k3_cand(
    const float* __restrict__ x, const uint32_t* __restrict__ aStar,
    uint32_t* __restrict__ cand, uint32_t* __restrict__ candCount,
    double* __restrict__ rowSumGt, int blocksPerRow, int cap, int n) {
    __shared__ uint32_t lbuf[LDSCAP];
    __shared__ uint32_t lcnt;
    __shared__ uint32_t gbase;
    if (threadIdx.x == 0) lcnt = 0;
    __syncthreads();

    int row   = blockIdx.x / blocksPerRow;
    int chunk = blockIdx.x % blocksPerRow;
    uint32_t a = aStar[row];
    uint32_t* cl = cand + (size_t)row * cap;
    uint32_t* cc = candCount + (size_t)row * CNT_STRIDE;
    const float4* p = (const float4*)(x + (size_t)row * n + (size_t)chunk * EPB);

    double s = 0.0;
    #pragma unroll 4
    for (int it = 0; it < ITERS; ++it) {
        float4 v = p[it * THREADS + threadIdx.x];
        float vals[4] = {v.x, v.y, v.z, v.w};
        #pragma unroll
        for (int j = 0; j < 4; ++j) {
            uint32_t u = f2u(vals[j]);
            uint32_t b = u >> 20;
            if (b > a) s += (double)vals[j];
            else if (b == a) {
                uint32_t pos = atomicAdd(&lcnt, 1u);   // LDS atomic, cheap
                if (pos < LDSCAP) lbuf[pos] = u;
                else {                                  // rare spill path
                    uint32_t g = atomicAdd(cc, 1u);
                    if ((int)g < cap) cl[g] = u;
                }
            }
        }
    }
    __syncthreads();
    uint32_t cnt = (lcnt < LDSCAP) ? lcnt : LDSCAP;
    if (threadIdx.x == 0) gbase = atomicAdd(cc, cnt);   // ONE global atomic/block
    __syncthreads();
    uint32_t base = gbase;
    for (uint32_t i = threadIdx.x; i < cnt; i += THREADS) {
        uint32_t g = base + i;
        if ((int)g < cap) cl[g] = lbuf[i];
    }
    double bs = blockReduceSum(s);
    if (threadIdx.x == 0) atomicAdd(&rowSumGt[row], bs);
}

// K4: two-pass select with per-bin double sums.
//  Pass A: 4096-bin hist+sum over bits[19:8] -> b1; sum of bins>b1 is the bulk
//          of the kept-sum.
//  Pass B: 256-bin hist+sum over bits[7:0] among bin==b1 -> b2. prefix|b1|b2
//          fixes ALL 32 bits, so the b2 slot elements all equal the threshold:
//          cnt256[b2]*u2f(uthr) completes the kept-sum. No further passes.
__global__ void __launch_bounds__(K4T) k4_final(
    const uint32_t* __restrict__ cand, const uint32_t* __restrict__ candCount,
    const uint32_t* __restrict__ aStar, const uint32_t* __restrict__ rankW,
    const double* __restrict__ rowSum, const double* __restrict__ rowSumGt,
    float* __restrict__ scaleArr, float* __restrict__ thrArr, int cap) {
    int row = blockIdx.x, tid = threadIdx.x;
    uint32_t c = candCount[(size_t)row * CNT_STRIDE];
    if (c > (uint32_t)cap) c = (uint32_t)cap;
    const uint32_t* cl = cand + (size_t)row * cap;

    __shared__ uint32_t hcnt[4096];
    __shared__ double   hsum[4096];
    __shared__ uint32_t part1[K4T];
    __shared__ uint32_t part2[64];
    __shared__ uint32_t cnt256[256];
    __shared__ double   sum256[256];
    __shared__ uint32_t sh_b1, sh_r2, sh_b2;

    for (int i = tid; i < 4096; i += K4T) { hcnt[i] = 0; hsum[i] = 0.0; }
    for (int i = tid; i < 256;  i += K4T) { cnt256[i] = 0; sum256[i] = 0.0; }
    __syncthreads();

    // Pass A
    for (uint32_t i = tid; i < c; i += K4T) {
        uint32_t u = cl[i];
        uint32_t b = (u >> 8) & 0xFFFu;
        atomicAdd(&hcnt[b], 1u);
        atomicAdd(&hsum[b], (double)u2f(u));
    }
    __syncthreads();

    // hierarchical rank scan: 1024 partials of 4 bins, 64 super-partials of 16
    uint32_t p1 = hcnt[tid*4] + hcnt[tid*4+1] + hcnt[tid*4+2] + hcnt[tid*4+3];
    part1[tid] = p1;
    __syncthreads();
    if (tid < 64) {
        uint32_t s2 = 0;
        for (int j = 0; j < 16; ++j) s2 += part1[tid*16 + j];
        part2[tid] = s2;
    }
    __syncthreads();
    if (tid == 0) {
        uint32_t r = rankW[row];              // 1-indexed within coarse bin
        uint32_t cum = 0;
        int j = 0;
        for (; j < 63; ++j) { if (cum + part2[j] >= r) break; cum += part2[j]; }
        int t = j * 16;
        for (; t < j*16 + 15; ++t) { if (cum + part1[t] >= r) break; cum += part1[t]; }
        int b = t * 4;
        for (; b < t*4 + 3; ++b) { if (cum + hcnt[b] >= r) break; cum += hcnt[b]; }
        sh_b1 = (uint32_t)b;
        sh_r2 = r - cum;                      // 1-indexed within b1
    }
    __syncthreads();
    uint32_t b1 = sh_b1;

    // kept-sum contribution from bins > b1
    double g = 0.0;
    for (int i = tid; i < 4096; i += K4T) if (i > (int)b1) g += hsum[i];

    // Pass B: low-byte hist+sum among bin==b1
    for (uint32_t i = tid; i < c; i += K4T) {
        uint32_t u = cl[i];
        if (((u >> 8) & 0xFFFu) == b1) {
            atomicAdd(&cnt256[u & 0xFFu], 1u);
            atomicAdd(&sum256[u & 0xFFu], (double)u2f(u));
        }
    }
    __syncthreads();
    if (tid == 0) {
        uint32_t r2 = sh_r2, cum = 0;
        int b = 0;
        for (; b < 255; ++b) { if (cum + cnt256[b] >= r2) break; cum += cnt256[b]; }
        sh_b2 = (uint32_t)b;
    }
    __syncthreads();
    uint32_t b2 = sh_b2;
    uint32_t uthr = (aStar[row] << 20) | (b1 << 8) | b2;

    double g2 = 0.0;
    for (int i = tid; i < 256; i += K4T) if (i > (int)b2) g2 += sum256[i];

    double tot = blockReduceSum(g + g2);
    if (tid == 0) {
        // elements in the b2 slot are bit-identical to the threshold
        tot += (double)cnt256[b2] * (double)u2f(uthr);
        double den = rowSumGt[row] + tot;
        double num = rowSum[row];
        double sc  = (den == 0.0) ? 0.0 : fabs(num / den);
        scaleArr[row] = (float)sc;
        thrArr[row]   = u2f(uthr);
    }
}

// K5: out = (x < thr) ? 0 : x * scale. Non-temporal stores keep x resident in
//     L2/L3 (x + out together exceed the 256MB L3; out is never re-read).
__global__ void __launch_bounds__(THREADS) k5_out(
    const float* __restrict__ x, float* __restrict__ out,
    const float* __restrict__ scaleArr, const float* __restrict__ thrArr,
    int blocksPerRow, int n) {
    int row   = blockIdx.x / blocksPerRow;
    int chunk = blockIdx.x % blocksPerRow;
    float sc = scaleArr[row];
    float th = thrArr[row];
    size_t base = (size_t)row * n + (size_t)chunk * EPB;
    const float4* p = (const float4*)(x + base);
    vfloat4* o = (vfloat4*)(out + base);
    #pragma unroll 4
    for (int it = 0; it < ITERS; ++it) {
        float4 v = p[it * THREADS + threadIdx.x];
        vfloat4 w;
        w.x = (v.x < th) ? 0.0f : v.x * sc;
        w.y = (v.y < th) ? 0.0f : v.y * sc;
        w.z = (v.z < th) ? 0.0f : v.z * sc;
        w.w = (v.w < th) ? 0.0f : v.w * sc;
        __builtin_nontemporal_store(w, &o[it * THREADS + threadIdx.x]);
    }
}

extern "C" void kernel_launch(void* const* d_in, const int* in_sizes, int n_in,
                              void* d_out, int out_size, void* d_ws, size_t ws_size,
                              hipStream_t stream) {
    const float* x     = (const float*)d_in[0];
    const float* probs = (const float*)d_in[1];
    float* out = (float*)d_out;

    int B = in_sizes[1];                     // 16
    long long total = in_sizes[0];           // 33554432
    int n = (int)(total / B);                // 2097152 per row
    int blocksPerRow = n / EPB;              // 64

    // workspace layout
    uint8_t* ws = (uint8_t*)d_ws;
    size_t off = 0;
    uint32_t* ghist = (uint32_t*)(ws + off); off += (size_t)B * NBINS * 4;
    double* rowSum    = (double*)(ws + off); off += (size_t)B * 8;
    double* rowSumGt  = (double*)(ws + off); off += (size_t)B * 8;
    uint32_t* aStar   = (uint32_t*)(ws + off); off += (size_t)B * 4;
    uint32_t* rankW   = (uint32_t*)(ws + off); off += (size_t)B * 4;
    uint32_t* candCnt = (uint32_t*)(ws + off); off += (size_t)B * CNT_STRIDE * 4;
    float* scaleArr   = (float*)(ws + off); off += (size_t)B * 4;
    float* thrArr     = (float*)(ws + off); off += (size_t)B * 4;
    off = (off + 255) & ~(size_t)255;
    size_t zeroBytes = off;
    size_t remain = (ws_size > off) ? (ws_size - off) : 0;
    int cap = (int)(remain / ((size_t)B * 4));
    if (cap > 262144) cap = 262144;
    if (cap < 1) cap = 1;
    uint32_t* cand = (uint32_t*)(ws + off);

    // zero accumulators every launch with our own kernel
    int n16 = (int)(zeroBytes / 16);
    k0_zero  <<<128,              THREADS, 0, stream>>>((uint4*)d_ws, n16);

    k1_hist  <<<B * blocksPerRow, THREADS, 0, stream>>>(x, ghist, rowSum, blocksPerRow, n);
    k2_select<<<B,                THREADS, 0, stream>>>(ghist, probs, aStar, rankW, n);
    k3_cand  <<<B * blocksPerRow, THREADS, 0, stream>>>(x, aStar, cand, candCnt, rowSumGt,
                                                        blocksPerRow, cap, n);
    k4_final <<<B,                K4T,     0, stream>>>(cand, candCnt, aStar, rankW,
                                                        rowSum, rowSumGt, scaleArr, thrArr, cap);
    k5_out   <<<B * blocksPerRow, THREADS, 0, stream>>>(x, out, scaleArr, thrArr, blocksPerRow, n);
}